// Round 4
// baseline (623.753 us; speedup 1.0000x reference)
//
#include <hip/hip_runtime.h>
#include <cstdint>

#define N_NODES 50000
#define N_EDGES 800000
#define IN_DIM  256
#define HID     128
#define T_STEPS 8

#define AG_LOAD(p)     __hip_atomic_load((p), __ATOMIC_RELAXED, __HIP_MEMORY_SCOPE_AGENT)
#define AG_STORE(p, v) __hip_atomic_store((p), (v), __ATOMIC_RELAXED, __HIP_MEMORY_SCOPE_AGENT)
#define AG_ADD(p, v)   __hip_atomic_fetch_add((p), (v), __ATOMIC_RELAXED, __HIP_MEMORY_SCOPE_AGENT)
#define AG_MIN(p, v)   __hip_atomic_fetch_min((p), (v), __ATOMIC_RELAXED, __HIP_MEMORY_SCOPE_AGENT)
#define AG_MAX(p, v)   __hip_atomic_fetch_max((p), (v), __ATOMIC_RELAXED, __HIP_MEMORY_SCOPE_AGENT)

typedef unsigned long long u64;

// ---------- float <-> orderable uint encoding for atomic min/max ----------
static __device__ __forceinline__ unsigned int enc_f(float f) {
    unsigned int u = __float_as_uint(f);
    return (u & 0x80000000u) ? ~u : (u | 0x80000000u);
}
static __device__ __forceinline__ float dec_f(unsigned int u) {
    unsigned int b = (u & 0x80000000u) ? (u ^ 0x80000000u) : ~u;
    return __uint_as_float(b);
}

// ---------- flag-array barrier, ZERO fences / ZERO acq_rel (R2-proven) ----------
static __device__ __forceinline__ void fbar(int* bar, int nblk, int t) {
    int* flags = bar;            // [nblk] monotone phase ids
    int* go    = bar + 1900;     // separate line
    __syncthreads();
    if (blockIdx.x == 0) {
        if (threadIdx.x == 0) AG_STORE(&flags[0], t);
        for (;;) {
            int ok = 1;
            for (int i = (int)threadIdx.x; i < nblk; i += 256)
                ok &= (AG_LOAD(&flags[i]) >= t);
            if (__syncthreads_and(ok)) break;
            __builtin_amdgcn_s_sleep(1);
        }
        if (threadIdx.x == 0) AG_STORE(go, t);
    } else {
        if (threadIdx.x == 0) {
            AG_STORE(&flags[blockIdx.x], t);
            while (AG_LOAD(go) < t) __builtin_amdgcn_s_sleep(4);
        }
        __syncthreads();
    }
}

// ================== MEGA: whole pipeline, one persistent kernel ==================
// R3 post-mortem: profiled 478us = 272 LIF + 206 prep; prep dominated by two
// 800K random-RMW passes that don't overlap the 50us VALU GEMM. R4 changes:
//  (1) GEMM split into 2 halves used as latency sponges for count / fill.
//  (2) fill: cursor pre-biased with row_ptr (1 RMW/edge, no random load);
//      packed int4{eid,src,attr} record -> ONE cache line per edge scatter.
//  (3) LIF edge loop unrolled x4: batch ds_reads, one LDS-latency exposure
//      per 4 edges. FP accumulation order unchanged (same ascending i).
template<int TNPB, int TNSLOT, int TECAP, int TMINW>
__global__ __launch_bounds__(256, TMINW) void k_mega(
    const float* __restrict__ x,
    const int*   __restrict__ spike_node,
    const int*   __restrict__ esrc,
    const int*   __restrict__ edst,
    const float* __restrict__ eattr,
    const float* __restrict__ W,
    const float* __restrict__ b,
    int* counts, int* cursor, int* row_ptr, int* blocksum,
    int4* edata4,
    unsigned int* mn_e, unsigned int* mx_e,
    uint32_t* sbA, uint32_t* sbB,
    float* __restrict__ out,
    int* bar, int nblk)
{
    __shared__ int      lrp[TNPB + 1];
    __shared__ uint32_t pool[TECAP * 6];
    __shared__ uint32_t sbw[TNPB][4];

    int*      ed_src_l  = (int*)pool;                 // [TECAP]   steady
    float*    ed_attr_l = (float*)(pool + TECAP);     // [TECAP]   steady
    uint32_t* ed_wds    = pool + 2 * TECAP;           // [TECAP*4] step loop
    float*    Ws        = (float*)pool;               // [4096]  gemm (transient)
    float*    xs        = (float*)(pool + 4096);      // [TNPB*36] gemm (transient)
    float*    red_mn    = (float*)pool;               // [1024] minmax (transient)
    float*    red_mx    = (float*)(pool + 1024);      // [1024]
    int*      rbuf      = (int*)pool;                 // [256]  scan (transient)
    int*      cnt_l     = (int*)sbw;                  // [TNPB] scan (transient)

    const int tid = threadIdx.x;
    const int bid = blockIdx.x;
    const int g   = tid >> 5, ln = tid & 31;
    const int n0  = bid * TNPB;
    const int ncnt = min(TNPB, N_NODES - n0);
    const int w = ln >> 3, shb = (ln & 7) * 4;
    const size_t NH = (size_t)N_NODES * HID;

    // GEMM state (registers) + chunk lambda (bit-identical FMA sequence)
    float4 hs[TNSLOT], vs[TNSLOT];
    uint32_t rcs[TNSLOT];
    #pragma unroll
    for (int s = 0; s < TNSLOT; ++s) hs[s] = make_float4(0.f, 0.f, 0.f, 0.f);
    int xoff[TNSLOT];
    #pragma unroll
    for (int s = 0; s < TNSLOT; ++s) xoff[s] = min(s * 8 + g, TNPB - 1) * 36;

    auto gemm_chunk = [&](int kc) {
        __syncthreads();
        for (int idx = tid; idx < TNPB * 8; idx += 256) {
            int node = idx >> 3, q = idx & 7;
            int row = min(n0 + node, N_NODES - 1);
            *(float4*)&xs[node * 36 + q * 4] =
                *(const float4*)(x + (size_t)row * IN_DIM + kc + q * 4);
        }
        for (int idx = tid; idx < 1024; idx += 256) {
            int r = idx >> 5, c = idx & 31;
            *(float4*)&Ws[r * 128 + c * 4] =
                *(const float4*)(W + (size_t)(kc + r) * HID + c * 4);
        }
        __syncthreads();
        #pragma unroll 4
        for (int k = 0; k < 32; ++k) {
            float4 wf = *(float4*)&Ws[k * 128 + ln * 4];
            #pragma unroll
            for (int s = 0; s < TNSLOT; ++s) {
                float xv = xs[xoff[s] + k];
                hs[s].x = __fmaf_rn(xv, wf.x, hs[s].x);
                hs[s].y = __fmaf_rn(xv, wf.y, hs[s].y);
                hs[s].z = __fmaf_rn(xv, wf.z, hs[s].z);
                hs[s].w = __fmaf_rn(xv, wf.w, hs[s].w);
            }
        }
    };

    // ---- P0: zero own counts; block0 inits mn/mx ----
    for (int i = tid; i < ncnt; i += 256) AG_STORE(&counts[n0 + i], 0);
    if (bid == 0 && tid < HID) {
        AG_STORE(&mn_e[tid], 0xFFFFFFFFu);
        AG_STORE(&mx_e[tid], 0u);
    }
    fbar(bar, nblk, 1);

    // ---- P1: issue count atomics (fire-and-forget), hide under GEMM 1st half ----
    for (int e = bid * 256 + tid; e < N_EDGES; e += nblk * 256)
        AG_ADD(&counts[edst[e]], 1);
    for (int kc = 0; kc < 128; kc += 32) gemm_chunk(kc);
    fbar(bar, nblk, 2);

    // ---- P2a: own-range degree sum -> blocksum ----
    for (int i = tid; i < ncnt; i += 256) cnt_l[i] = AG_LOAD(&counts[n0 + i]);
    __syncthreads();
    if (tid == 0) {
        int s = 0;
        for (int i = 0; i < ncnt; ++i) s += cnt_l[i];
        AG_STORE(&blocksum[bid], s);
    }
    fbar(bar, nblk, 3);

    // ---- P2b: exclusive base + own row_ptr; cursor pre-biased (absolute) ----
    {
        int part = 0;
        for (int j = tid; j < bid; j += 256) part += AG_LOAD(&blocksum[j]);
        rbuf[tid] = part;
        __syncthreads();
        for (int off = 128; off > 0; off >>= 1) {
            if (tid < off) rbuf[tid] += rbuf[tid + off];
            __syncthreads();
        }
        if (tid == 0) {
            int run = rbuf[0];
            for (int i = 0; i < ncnt; ++i) { lrp[i] = run; run += cnt_l[i]; }
            lrp[ncnt] = run;
        }
        __syncthreads();
        for (int i = tid; i <= ncnt; i += 256) AG_STORE(&row_ptr[n0 + i], lrp[i]);
        for (int i = tid; i < ncnt; i += 256) AG_STORE(&cursor[n0 + i], lrp[i]);
    }
    fbar(bar, nblk, 4);

    // ---- P3: fill (1 RMW + same-line 16B record), hide under GEMM 2nd half ----
    for (int e = bid * 256 + tid; e < N_EDGES; e += nblk * 256) {
        int d = edst[e];
        int p = AG_ADD(&cursor[d], 1);
        u64 a  = (u64)(unsigned int)e | ((u64)(unsigned int)esrc[e] << 32);
        u64 bq = (u64)__float_as_uint(eattr[e]);
        u64* qp = (u64*)&edata4[p];
        AG_STORE(qp, a);
        AG_STORE(qp + 1, bq);
    }
    for (int kc = 128; kc < 256; kc += 32) gemm_chunk(kc);

    // ---- P4b: bias + minmax reduce + global push ----
    {
        float4 bv = *(const float4*)(b + ln * 4);
        float lmn[4], lmx[4];
        #pragma unroll
        for (int c = 0; c < 4; ++c) { lmn[c] = INFINITY; lmx[c] = -INFINITY; }
        #pragma unroll
        for (int s = 0; s < TNSLOT; ++s) {
            hs[s].x = __fadd_rn(hs[s].x, bv.x);
            hs[s].y = __fadd_rn(hs[s].y, bv.y);
            hs[s].z = __fadd_rn(hs[s].z, bv.z);
            hs[s].w = __fadd_rn(hs[s].w, bv.w);
            lmn[0] = fminf(lmn[0], hs[s].x); lmx[0] = fmaxf(lmx[0], hs[s].x);
            lmn[1] = fminf(lmn[1], hs[s].y); lmx[1] = fmaxf(lmx[1], hs[s].y);
            lmn[2] = fminf(lmn[2], hs[s].z); lmx[2] = fmaxf(lmx[2], hs[s].z);
            lmn[3] = fminf(lmn[3], hs[s].w); lmx[3] = fmaxf(lmx[3], hs[s].w);
        }
        __syncthreads();                       // Ws/xs dead
        #pragma unroll
        for (int c = 0; c < 4; ++c) {
            red_mn[g * 128 + ln * 4 + c] = lmn[c];
            red_mx[g * 128 + ln * 4 + c] = lmx[c];
        }
        __syncthreads();
        if (tid < 128) {
            float mnv = red_mn[tid], mxv = red_mx[tid];
            #pragma unroll
            for (int r = 1; r < 8; ++r) {
                mnv = fminf(mnv, red_mn[r * 128 + tid]);
                mxv = fmaxf(mxv, red_mx[r * 128 + tid]);
            }
            AG_MIN(&mn_e[tid], enc_f(mnv));
            AG_MAX(&mx_e[tid], enc_f(mxv));
        }
        __syncthreads();                       // red dead
    }
    fbar(bar, nblk, 5);       // fill + minmax globally complete

    const int ebase = lrp[0];
    const int etot  = lrp[ncnt] - ebase;
    const bool inlds = (etot <= TECAP);

    // ---- P5: spike-init stores (drain under sort), normalize, sort->LDS ----
    for (int i = tid; i < ncnt; i += 256) {
        uint32_t f = spike_node[n0 + i] ? 0xFFFFFFFFu : 0u;
        u64 ff = (u64)f | ((u64)f << 32);
        AG_STORE((u64*)&sbA[(size_t)(n0 + i) * 4], ff);
        AG_STORE((u64*)&sbA[(size_t)(n0 + i) * 4 + 2], ff);
    }
    {
        float mn0 = dec_f(AG_LOAD(&mn_e[ln * 4 + 0]));
        float mn1 = dec_f(AG_LOAD(&mn_e[ln * 4 + 1]));
        float mn2 = dec_f(AG_LOAD(&mn_e[ln * 4 + 2]));
        float mn3 = dec_f(AG_LOAD(&mn_e[ln * 4 + 3]));
        float dd0 = __fadd_rn(__fsub_rn(dec_f(AG_LOAD(&mx_e[ln * 4 + 0])), mn0), 1e-6f);
        float dd1 = __fadd_rn(__fsub_rn(dec_f(AG_LOAD(&mx_e[ln * 4 + 1])), mn1), 1e-6f);
        float dd2 = __fadd_rn(__fsub_rn(dec_f(AG_LOAD(&mx_e[ln * 4 + 2])), mn2), 1e-6f);
        float dd3 = __fadd_rn(__fsub_rn(dec_f(AG_LOAD(&mx_e[ln * 4 + 3])), mn3), 1e-6f);
        #pragma unroll
        for (int s = 0; s < TNSLOT; ++s) {
            hs[s].x = __fdiv_rn(__fsub_rn(hs[s].x, mn0), dd0);
            hs[s].y = __fdiv_rn(__fsub_rn(hs[s].y, mn1), dd1);
            hs[s].z = __fdiv_rn(__fsub_rn(hs[s].z, mn2), dd2);
            hs[s].w = __fdiv_rn(__fsub_rn(hs[s].w, mn3), dd3);
        }
    }
    #pragma unroll
    for (int s = 0; s < TNSLOT; ++s) { vs[s] = make_float4(0.f,0.f,0.f,0.f); rcs[s] = 0u; }

    if (inlds) {
        for (int m = tid >> 6; m < ncnt; m += 4) {
            int l = tid & 63;
            int gbeg = lrp[m], lbeg = gbeg - ebase;
            int cnt = lrp[m + 1] - gbeg;
            if (cnt <= 0) continue;
            if (cnt <= 64) {
                int key = 0x7FFFFFFF, sv = 0, av = 0;
                if (l < cnt) {
                    u64 a  = AG_LOAD((u64*)&edata4[gbeg + l]);
                    u64 bq = AG_LOAD((u64*)&edata4[gbeg + l] + 1);
                    key = (int)(unsigned int)a;
                    sv  = (int)(unsigned int)(a >> 32);
                    av  = (int)(unsigned int)bq;
                }
                #pragma unroll
                for (int k = 2; k <= 64; k <<= 1) {
                    for (int j = k >> 1; j > 0; j >>= 1) {
                        int pk2 = __shfl_xor(key, j);
                        int ps  = __shfl_xor(sv, j);
                        int pa  = __shfl_xor(av, j);
                        bool lower = (l & j) == 0;
                        bool asc   = (l & k) == 0;
                        bool take  = (lower == asc) ? (pk2 < key) : (pk2 > key);
                        if (take) { key = pk2; sv = ps; av = pa; }
                    }
                }
                if (l < cnt) {
                    ed_src_l[lbeg + l]  = sv;
                    ed_attr_l[lbeg + l] = __int_as_float(av);
                }
            } else {
                if (l == 0) {          // robustness path; dead for this input
                    for (int i = 1; i < cnt; ++i) {
                        u64 ka = AG_LOAD((u64*)&edata4[gbeg + i]);
                        u64 kb = AG_LOAD((u64*)&edata4[gbeg + i] + 1);
                        int ke = (int)(unsigned int)ka;
                        int mm = i - 1;
                        while (mm >= 0) {
                            u64 ma = AG_LOAD((u64*)&edata4[gbeg + mm]);
                            if ((int)(unsigned int)ma <= ke) break;
                            AG_STORE((u64*)&edata4[gbeg + mm + 1], ma);
                            AG_STORE((u64*)&edata4[gbeg + mm + 1] + 1,
                                     AG_LOAD((u64*)&edata4[gbeg + mm] + 1));
                            --mm;
                        }
                        AG_STORE((u64*)&edata4[gbeg + mm + 1], ka);
                        AG_STORE((u64*)&edata4[gbeg + mm + 1] + 1, kb);
                    }
                }
                for (int i = l; i < cnt; i += 64) {
                    u64 a  = AG_LOAD((u64*)&edata4[gbeg + i]);
                    u64 bq = AG_LOAD((u64*)&edata4[gbeg + i] + 1);
                    ed_src_l[lbeg + i]  = (int)(unsigned int)(a >> 32);
                    ed_attr_l[lbeg + i] = __uint_as_float((unsigned int)bq);
                }
            }
        }
    } else {                           // overflow: sort global in place (dead)
        for (int m = tid >> 6; m < ncnt; m += 4) {
            int l = tid & 63;
            int gbeg = lrp[m];
            int cnt = lrp[m + 1] - gbeg;
            if (cnt <= 1) continue;
            if (cnt <= 64) {
                int key = 0x7FFFFFFF, sv = 0, av = 0;
                if (l < cnt) {
                    u64 a  = AG_LOAD((u64*)&edata4[gbeg + l]);
                    u64 bq = AG_LOAD((u64*)&edata4[gbeg + l] + 1);
                    key = (int)(unsigned int)a;
                    sv  = (int)(unsigned int)(a >> 32);
                    av  = (int)(unsigned int)bq;
                }
                #pragma unroll
                for (int k = 2; k <= 64; k <<= 1) {
                    for (int j = k >> 1; j > 0; j >>= 1) {
                        int pk2 = __shfl_xor(key, j);
                        int ps  = __shfl_xor(sv, j);
                        int pa  = __shfl_xor(av, j);
                        bool lower = (l & j) == 0;
                        bool asc   = (l & k) == 0;
                        bool take  = (lower == asc) ? (pk2 < key) : (pk2 > key);
                        if (take) { key = pk2; sv = ps; av = pa; }
                    }
                }
                if (l < cnt) {
                    u64 a = (u64)(unsigned int)key | ((u64)(unsigned int)sv << 32);
                    AG_STORE((u64*)&edata4[gbeg + l], a);
                    AG_STORE((u64*)&edata4[gbeg + l] + 1, (u64)(unsigned int)av);
                }
            } else if (l == 0) {
                for (int i = 1; i < cnt; ++i) {
                    u64 ka = AG_LOAD((u64*)&edata4[gbeg + i]);
                    u64 kb = AG_LOAD((u64*)&edata4[gbeg + i] + 1);
                    int ke = (int)(unsigned int)ka;
                    int mm = i - 1;
                    while (mm >= 0) {
                        u64 ma = AG_LOAD((u64*)&edata4[gbeg + mm]);
                        if ((int)(unsigned int)ma <= ke) break;
                        AG_STORE((u64*)&edata4[gbeg + mm + 1], ma);
                        AG_STORE((u64*)&edata4[gbeg + mm + 1] + 1,
                                 AG_LOAD((u64*)&edata4[gbeg + mm] + 1));
                        --mm;
                    }
                    AG_STORE((u64*)&edata4[gbeg + mm + 1], ka);
                    AG_STORE((u64*)&edata4[gbeg + mm + 1] + 1, kb);
                }
            }
        }
    }
    for (int i = tid; i < ncnt * 2; i += 256) ((u64*)sbw)[i] = 0ull;
    fbar(bar, nblk, 6);

    // ---- 8-step LIF ----
    for (int t = 0; t < T_STEPS; ++t) {
        const uint32_t* cur = (t & 1) ? sbB : sbA;
        uint32_t*       nxt = (t & 1) ? sbA : sbB;
        if (t > 0) fbar(bar, nblk, 6 + t);

        if (inlds) {
            for (int i = tid; i < etot; i += 256) {
                u64* sp = (u64*)&cur[(size_t)ed_src_l[i] * 4];
                u64 lo = AG_LOAD(sp);
                u64 hi = AG_LOAD(sp + 1);
                uint4 wv;
                wv.x = (uint32_t)lo; wv.y = (uint32_t)(lo >> 32);
                wv.z = (uint32_t)hi; wv.w = (uint32_t)(hi >> 32);
                *(uint4*)&ed_wds[i * 4] = wv;
            }
        }
        __syncthreads();

        #pragma unroll
        for (int s = 0; s < TNSLOT; ++s) {
            int m = s * 8 + g;
            if (m < ncnt) {
                float ag0 = 0.f, ag1 = 0.f, ag2 = 0.f, ag3 = 0.f;
                if (inlds) {
                    int lb = lrp[m] - ebase, le = lrp[m + 1] - ebase;
                    int i = lb;
                    // unroll x4: batch the LDS reads, keep ascending add order
                    for (; i + 4 <= le; i += 4) {
                        uint32_t u0 = ed_wds[(i+0) * 4 + w]; float a0 = ed_attr_l[i+0];
                        uint32_t u1 = ed_wds[(i+1) * 4 + w]; float a1 = ed_attr_l[i+1];
                        uint32_t u2 = ed_wds[(i+2) * 4 + w]; float a2 = ed_attr_l[i+2];
                        uint32_t u3 = ed_wds[(i+3) * 4 + w]; float a3 = ed_attr_l[i+3];
                        uint32_t b0 = (u0 >> shb) & 0xFu;
                        uint32_t b1 = (u1 >> shb) & 0xFu;
                        uint32_t b2 = (u2 >> shb) & 0xFu;
                        uint32_t b3 = (u3 >> shb) & 0xFu;
                        ag0 = __fadd_rn(ag0, (b0 & 1u) ? a0 : 0.f);
                        ag1 = __fadd_rn(ag1, (b0 & 2u) ? a0 : 0.f);
                        ag2 = __fadd_rn(ag2, (b0 & 4u) ? a0 : 0.f);
                        ag3 = __fadd_rn(ag3, (b0 & 8u) ? a0 : 0.f);
                        ag0 = __fadd_rn(ag0, (b1 & 1u) ? a1 : 0.f);
                        ag1 = __fadd_rn(ag1, (b1 & 2u) ? a1 : 0.f);
                        ag2 = __fadd_rn(ag2, (b1 & 4u) ? a1 : 0.f);
                        ag3 = __fadd_rn(ag3, (b1 & 8u) ? a1 : 0.f);
                        ag0 = __fadd_rn(ag0, (b2 & 1u) ? a2 : 0.f);
                        ag1 = __fadd_rn(ag1, (b2 & 2u) ? a2 : 0.f);
                        ag2 = __fadd_rn(ag2, (b2 & 4u) ? a2 : 0.f);
                        ag3 = __fadd_rn(ag3, (b2 & 8u) ? a2 : 0.f);
                        ag0 = __fadd_rn(ag0, (b3 & 1u) ? a3 : 0.f);
                        ag1 = __fadd_rn(ag1, (b3 & 2u) ? a3 : 0.f);
                        ag2 = __fadd_rn(ag2, (b3 & 4u) ? a3 : 0.f);
                        ag3 = __fadd_rn(ag3, (b3 & 8u) ? a3 : 0.f);
                    }
                    for (; i < le; ++i) {
                        uint32_t u = ed_wds[i * 4 + w];
                        float a = ed_attr_l[i];
                        uint32_t bits = (u >> shb) & 0xFu;
                        ag0 = __fadd_rn(ag0, (bits & 1u) ? a : 0.f);
                        ag1 = __fadd_rn(ag1, (bits & 2u) ? a : 0.f);
                        ag2 = __fadd_rn(ag2, (bits & 4u) ? a : 0.f);
                        ag3 = __fadd_rn(ag3, (bits & 8u) ? a : 0.f);
                    }
                } else {
                    int lb = lrp[m], le = lrp[m + 1];
                    for (int i = lb; i < le; ++i) {
                        u64 a  = AG_LOAD((u64*)&edata4[i]);
                        u64 bq = AG_LOAD((u64*)&edata4[i] + 1);
                        int srcn = (int)(unsigned int)(a >> 32);
                        float av = __uint_as_float((unsigned int)bq);
                        uint32_t u = AG_LOAD((uint32_t*)&cur[(size_t)srcn * 4 + w]);
                        uint32_t bits = (u >> shb) & 0xFu;
                        ag0 = __fadd_rn(ag0, (bits & 1u) ? av : 0.f);
                        ag1 = __fadd_rn(ag1, (bits & 2u) ? av : 0.f);
                        ag2 = __fadd_rn(ag2, (bits & 4u) ? av : 0.f);
                        ag3 = __fadd_rn(ag3, (bits & 8u) ? av : 0.f);
                    }
                }

                float hv[4] = {hs[s].x, hs[s].y, hs[s].z, hs[s].w};
                float vv[4] = {vs[s].x, vs[s].y, vs[s].z, vs[s].w};
                float ag[4] = {ag0, ag1, ag2, ag3};
                float vf[4], sf[4];
                uint32_t rcu = rcs[s], rcn = 0u, nib = 0u;
                #pragma unroll
                for (int q = 0; q < 4; ++q) {
                    float vn = __fadd_rn(__fadd_rn(__fmul_rn(0.8f, vv[q]), hv[q]), ag[q]);
                    uint32_t rc = (rcu >> (8 * q)) & 0xFFu;
                    bool spk = (vn >= 0.5f) && (rc == 0u);
                    vf[q] = spk ? 0.0f : vn;
                    sf[q] = spk ? 1.0f : 0.0f;
                    uint32_t rnew = spk ? 2u : (rc > 0u ? rc - 1u : 0u);
                    rcn |= rnew << (8 * q);
                    nib |= (spk ? 1u : 0u) << q;
                }
                vs[s] = make_float4(vf[0], vf[1], vf[2], vf[3]);
                rcs[s] = rcn;
                size_t idx = (size_t)(n0 + m) * HID + ln * 4;
                *(float4*)&out[NH + (size_t)t * NH + idx] =
                    make_float4(sf[0], sf[1], sf[2], sf[3]);
                if (t == T_STEPS - 1) {
                    *(float4*)&out[idx] = make_float4(
                        __fadd_rn(hv[0], __fmul_rn(0.5f, vf[0])),
                        __fadd_rn(hv[1], __fmul_rn(0.5f, vf[1])),
                        __fadd_rn(hv[2], __fmul_rn(0.5f, vf[2])),
                        __fadd_rn(hv[3], __fmul_rn(0.5f, vf[3])));
                }
                atomicOr(&sbw[m][w], nib << shb);
            }
        }
        __syncthreads();
        for (int i = tid; i < ncnt * 2; i += 256) {   // publish (LLC) + re-zero, 64b
            AG_STORE((u64*)&nxt[(size_t)n0 * 4] + i, ((u64*)sbw)[i]);
            ((u64*)sbw)[i] = 0ull;
        }
    }
}

// ================== fallback pipeline (unchanged, R2-proven) ==================
__global__ void k_count(const int* __restrict__ dst, int* __restrict__ counts) {
    int e = blockIdx.x * blockDim.x + threadIdx.x;
    if (e < N_EDGES) atomicAdd(&counts[dst[e]], 1);
}

__global__ void k_scan1(const int* __restrict__ counts, int* __restrict__ row_tmp,
                        int* __restrict__ blocksum) {
    __shared__ int sh[256];
    int t = threadIdx.x, i = blockIdx.x * 256 + t;
    int c = (i < N_NODES) ? counts[i] : 0;
    sh[t] = c; __syncthreads();
    for (int off = 1; off < 256; off <<= 1) {
        int val = (t >= off) ? sh[t - off] : 0;
        __syncthreads();
        sh[t] += val;
        __syncthreads();
    }
    if (i < N_NODES) row_tmp[i] = sh[t] - c;
    if (t == 255) blocksum[blockIdx.x] = sh[255];
}

__global__ void k_scan2(const int* __restrict__ blocksum, int* __restrict__ blockoff,
                        int nb, int* __restrict__ row_ptr) {
    if (threadIdx.x == 0) {
        int acc = 0;
        for (int b = 0; b < nb; ++b) { blockoff[b] = acc; acc += blocksum[b]; }
        row_ptr[N_NODES] = acc;
    }
}

__global__ void k_scan3(const int* __restrict__ row_tmp, const int* __restrict__ blockoff,
                        int* __restrict__ row_ptr) {
    int i = blockIdx.x * blockDim.x + threadIdx.x;
    if (i < N_NODES) row_ptr[i] = row_tmp[i] + blockoff[i >> 8];
}

__global__ void k_fill(const int* __restrict__ dst, const int* __restrict__ src,
                       const float* __restrict__ attr,
                       const int* __restrict__ row_ptr, int* __restrict__ cursor,
                       int* __restrict__ eid, int2* __restrict__ edata) {
    int e = blockIdx.x * blockDim.x + threadIdx.x;
    if (e >= N_EDGES) return;
    int d = dst[e];
    int p = row_ptr[d] + atomicAdd(&cursor[d], 1);
    eid[p]   = e;
    edata[p] = make_int2(src[e], __float_as_int(attr[e]));
}

__global__ __launch_bounds__(256) void k_bsort(const int* __restrict__ row_ptr,
                                               int* __restrict__ eid,
                                               int2* __restrict__ edata) {
    int node = blockIdx.x * 4 + (threadIdx.x >> 6);
    int l = threadIdx.x & 63;
    int beg = row_ptr[node], end = row_ptr[node + 1], cnt = end - beg;
    if (cnt <= 1) return;
    if (cnt <= 64) {
        int key = 0x7FFFFFFF, sv = 0, av = 0;
        if (l < cnt) { key = eid[beg + l]; int2 d = edata[beg + l]; sv = d.x; av = d.y; }
        #pragma unroll
        for (int k = 2; k <= 64; k <<= 1) {
            for (int j = k >> 1; j > 0; j >>= 1) {
                int pk = __shfl_xor(key, j);
                int ps = __shfl_xor(sv, j);
                int pa = __shfl_xor(av, j);
                bool lower = (l & j) == 0;
                bool asc   = (l & k) == 0;
                bool take = ((lower == asc)) ? (pk < key) : (pk > key);
                if (take) { key = pk; sv = ps; av = pa; }
            }
        }
        if (l < cnt) { eid[beg + l] = key; edata[beg + l] = make_int2(sv, av); }
    } else if (l == 0) {
        for (int i = beg + 1; i < end; ++i) {
            int ke = eid[i]; int2 kd = edata[i];
            int m = i - 1;
            while (m >= beg && eid[m] > ke) {
                eid[m+1] = eid[m]; edata[m+1] = edata[m]; --m;
            }
            eid[m+1] = ke; edata[m+1] = kd;
        }
    }
}

__global__ __launch_bounds__(256) void k_gemm(const float* __restrict__ x,
                                              const float* __restrict__ W,
                                              const float* __restrict__ b,
                                              float* __restrict__ h,
                                              unsigned int* __restrict__ mn_e,
                                              unsigned int* __restrict__ mx_e) {
    __shared__ float Ws[32 * 128];
    __shared__ float xs[64 * 36];
    __shared__ float red_mn[8 * 128];
    __shared__ float red_mx[8 * 128];
    const int tid = threadIdx.x;
    const int n0 = blockIdx.x * 64;
    const int jt = tid & 31, nt = tid >> 5;
    const int j0 = jt * 4;

    float acc[8][4];
    #pragma unroll
    for (int a = 0; a < 8; ++a)
        #pragma unroll
        for (int c = 0; c < 4; ++c) acc[a][c] = 0.0f;

    const int ldn = tid >> 2;
    const int kq  = (tid & 3) * 8;
    const int xrow = (n0 + ldn < N_NODES) ? (n0 + ldn) : (N_NODES - 1);
    const float* xg = x + (size_t)xrow * IN_DIM;

    for (int kc = 0; kc < IN_DIM; kc += 32) {
        __syncthreads();
        float4 xa = *(const float4*)(xg + kc + kq);
        float4 xb = *(const float4*)(xg + kc + kq + 4);
        *(float4*)&xs[ldn * 36 + kq]     = xa;
        *(float4*)&xs[ldn * 36 + kq + 4] = xb;
        #pragma unroll
        for (int p = 0; p < 4; ++p) {
            int r = nt + p * 8;
            *(float4*)&Ws[r * 128 + j0] =
                *(const float4*)(W + (size_t)(kc + r) * HID + j0);
        }
        __syncthreads();
        const float* xbase = &xs[nt * 8 * 36];
        #pragma unroll 4
        for (int k = 0; k < 32; ++k) {
            float4 wf = *(const float4*)&Ws[k * 128 + j0];
            #pragma unroll
            for (int ni = 0; ni < 8; ++ni) {
                float xv = xbase[ni * 36 + k];
                acc[ni][0] = __fmaf_rn(xv, wf.x, acc[ni][0]);
                acc[ni][1] = __fmaf_rn(xv, wf.y, acc[ni][1]);
                acc[ni][2] = __fmaf_rn(xv, wf.z, acc[ni][2]);
                acc[ni][3] = __fmaf_rn(xv, wf.w, acc[ni][3]);
            }
        }
    }

    float4 bv = *(const float4*)(b + j0);
    float lmn[4], lmx[4];
    #pragma unroll
    for (int c = 0; c < 4; ++c) { lmn[c] = INFINITY; lmx[c] = -INFINITY; }
    #pragma unroll
    for (int ni = 0; ni < 8; ++ni) {
        acc[ni][0] = __fadd_rn(acc[ni][0], bv.x);
        acc[ni][1] = __fadd_rn(acc[ni][1], bv.y);
        acc[ni][2] = __fadd_rn(acc[ni][2], bv.z);
        acc[ni][3] = __fadd_rn(acc[ni][3], bv.w);
        #pragma unroll
        for (int c = 0; c < 4; ++c) {
            lmn[c] = fminf(lmn[c], acc[ni][c]);
            lmx[c] = fmaxf(lmx[c], acc[ni][c]);
        }
    }
    #pragma unroll
    for (int c = 0; c < 4; ++c) {
        red_mn[nt * 128 + j0 + c] = lmn[c];
        red_mx[nt * 128 + j0 + c] = lmx[c];
    }
    __syncthreads();
    if (tid < 128) {
        float mnv = red_mn[tid], mxv = red_mx[tid];
        #pragma unroll
        for (int r = 1; r < 8; ++r) {
            mnv = fminf(mnv, red_mn[r * 128 + tid]);
            mxv = fmaxf(mxv, red_mx[r * 128 + tid]);
        }
        atomicMin(&mn_e[tid], enc_f(mnv));
        atomicMax(&mx_e[tid], enc_f(mxv));
    }
    #pragma unroll
    for (int ni = 0; ni < 8; ++ni) {
        int n = n0 + nt * 8 + ni;
        if (n < N_NODES)
            *(float4*)&h[(size_t)n * HID + j0] =
                make_float4(acc[ni][0], acc[ni][1], acc[ni][2], acc[ni][3]);
    }
}

__global__ void k_init_bits(const int* __restrict__ spike_node, uint32_t* __restrict__ sb) {
    int n = blockIdx.x * blockDim.x + threadIdx.x;
    if (n >= N_NODES) return;
    uint32_t f = spike_node[n] ? 0xFFFFFFFFu : 0u;
    sb[(size_t)n * 4 + 0] = f;
    sb[(size_t)n * 4 + 1] = f;
    sb[(size_t)n * 4 + 2] = f;
    sb[(size_t)n * 4 + 3] = f;
}

__global__ __launch_bounds__(128) void k_step(const int* __restrict__ row_ptr,
                                              const int2* __restrict__ edata,
                                              const uint32_t* __restrict__ sb_cur,
                                              uint32_t* __restrict__ sb_nxt,
                                              float* __restrict__ h,
                                              float* __restrict__ v,
                                              unsigned char* __restrict__ refc,
                                              const unsigned int* __restrict__ mn_e,
                                              const unsigned int* __restrict__ mx_e,
                                              float* __restrict__ out_spk,
                                              float* __restrict__ out_fus,
                                              int t0, int is_last) {
    __shared__ float    attr_l[4][128];
    __shared__ uint32_t words_l[4][128][4];
    __shared__ uint32_t sbw[16];
    __shared__ int      rp[5];

    const int tid = threadIdx.x;
    const int ns = tid >> 5, ln = tid & 31;
    const int nb = blockIdx.x * 4;
    const int n  = nb + ns;

    if (tid < 16) sbw[tid] = 0;
    if (tid < 5)  rp[tid] = row_ptr[nb + tid];
    __syncthreads();

    const int beg = rp[ns], cnt = rp[ns + 1] - beg;
    int cmax = 0;
    #pragma unroll
    for (int q = 0; q < 4; ++q) cmax = max(cmax, rp[q + 1] - rp[q]);
    const int nchunk = (cmax + 127) >> 7;

    float agg0 = 0.f, agg1 = 0.f, agg2 = 0.f, agg3 = 0.f;
    const int w = ln >> 3, shb = (ln & 7) * 4;

    for (int ch = 0; ch < nchunk; ++ch) {
        int base = ch << 7;
        __syncthreads();
        #pragma unroll
        for (int rep = 0; rep < 4; ++rep) {
            int i = base + rep * 32 + ln;
            if (i < cnt) {
                int2 d = edata[beg + i];
                attr_l[ns][rep * 32 + ln] = __int_as_float(d.y);
                *(uint4*)&words_l[ns][rep * 32 + ln][0] =
                    *(const uint4*)&sb_cur[(size_t)d.x * 4];
            }
        }
        __syncthreads();
        int lim = min(128, cnt - base);
        for (int i = 0; i < lim; ++i) {
            uint32_t u = words_l[ns][i][w];
            float a = attr_l[ns][i];
            uint32_t bits = (u >> shb) & 0xFu;
            agg0 = __fadd_rn(agg0, (bits & 1u) ? a : 0.0f);
            agg1 = __fadd_rn(agg1, (bits & 2u) ? a : 0.0f);
            agg2 = __fadd_rn(agg2, (bits & 4u) ? a : 0.0f);
            agg3 = __fadd_rn(agg3, (bits & 8u) ? a : 0.0f);
        }
    }

    const size_t idx = (size_t)n * HID + ln * 4;
    float4 h4 = *(const float4*)&h[idx];
    if (t0) {
        const int jb = ln * 4;
        float hq[4] = {h4.x, h4.y, h4.z, h4.w};
        #pragma unroll
        for (int q = 0; q < 4; ++q) {
            float mn = dec_f(mn_e[jb + q]);
            float mx = dec_f(mx_e[jb + q]);
            float d2 = __fadd_rn(__fsub_rn(mx, mn), 1e-6f);
            hq[q] = __fdiv_rn(__fsub_rn(hq[q], mn), d2);
        }
        h4 = make_float4(hq[0], hq[1], hq[2], hq[3]);
        *(float4*)&h[idx] = h4;
    }
    float4 v4;
    unsigned int rcu;
    if (t0) { v4 = make_float4(0.f, 0.f, 0.f, 0.f); rcu = 0u; }
    else    { v4 = *(const float4*)&v[idx]; rcu = *(const unsigned int*)&refc[idx]; }

    float hv[4]  = {h4.x, h4.y, h4.z, h4.w};
    float vv[4]  = {v4.x, v4.y, v4.z, v4.w};
    float ag[4]  = {agg0, agg1, agg2, agg3};
    float vf[4], sf[4];
    unsigned int rcn = 0u, nib = 0u;
    #pragma unroll
    for (int q = 0; q < 4; ++q) {
        float vn = __fadd_rn(__fadd_rn(__fmul_rn(0.8f, vv[q]), hv[q]), ag[q]);
        unsigned int rc = (rcu >> (8 * q)) & 0xFFu;
        bool spk = (vn >= 0.5f) && (rc == 0u);
        vf[q] = spk ? 0.0f : vn;
        sf[q] = spk ? 1.0f : 0.0f;
        unsigned int rnew = spk ? 2u : (rc > 0u ? rc - 1u : 0u);
        rcn |= rnew << (8 * q);
        nib |= (spk ? 1u : 0u) << q;
    }
    *(float4*)&v[idx] = make_float4(vf[0], vf[1], vf[2], vf[3]);
    *(unsigned int*)&refc[idx] = rcn;
    *(float4*)&out_spk[idx] = make_float4(sf[0], sf[1], sf[2], sf[3]);
    if (is_last) {
        *(float4*)&out_fus[idx] = make_float4(
            __fadd_rn(hv[0], __fmul_rn(0.5f, vf[0])),
            __fadd_rn(hv[1], __fmul_rn(0.5f, vf[1])),
            __fadd_rn(hv[2], __fmul_rn(0.5f, vf[2])),
            __fadd_rn(hv[3], __fmul_rn(0.5f, vf[3])));
    }
    atomicOr(&sbw[ns * 4 + w], nib << shb);
    __syncthreads();
    if (tid < 16)
        sb_nxt[(size_t)(nb + (tid >> 2)) * 4 + (tid & 3)] = sbw[tid];
}

extern "C" void kernel_launch(void* const* d_in, const int* in_sizes, int n_in,
                              void* d_out, int out_size, void* d_ws, size_t ws_size,
                              hipStream_t stream) {
    const float* x          = (const float*)d_in[0];
    const int*   spike_node = (const int*)  d_in[1];
    const int*   edge_index = (const int*)  d_in[2];   // [2][E]
    const float* edge_attr  = (const float*)d_in[4];
    const float* W          = (const float*)d_in[5];
    const float* b          = (const float*)d_in[6];
    float* out = (float*)d_out;

    const int* src = edge_index;
    const int* dst = edge_index + N_EDGES;

    char* wsp = (char*)d_ws;
    auto alloc = [&](size_t bytes) {
        char* p = wsp;
        wsp += (bytes + 255) & ~(size_t)255;
        return p;
    };
    float*         h        = (float*)        alloc((size_t)N_NODES * HID * 4);
    float*         v        = (float*)        alloc((size_t)N_NODES * HID * 4);
    unsigned char* refc     = (unsigned char*)alloc((size_t)N_NODES * HID);
    uint32_t*      sbA      = (uint32_t*)     alloc((size_t)N_NODES * 16);
    uint32_t*      sbB      = (uint32_t*)     alloc((size_t)N_NODES * 16);
    int*           counts   = (int*)          alloc((size_t)N_NODES * 4);
    int*           cursor   = (int*)          alloc((size_t)N_NODES * 4);
    int*           row_tmp  = (int*)          alloc((size_t)N_NODES * 4);
    int*           row_ptr  = (int*)          alloc((size_t)(N_NODES + 1) * 4);
    int*           blocksum = (int*)          alloc(1024 * 4);
    int*           blockoff = (int*)          alloc(1024 * 4);
    int*           eid      = (int*)          alloc((size_t)N_EDGES * 4);
    int2*          edata    = (int2*)         alloc((size_t)N_EDGES * 8);
    unsigned int*  mn_e     = (unsigned int*) alloc(HID * 4);
    unsigned int*  mx_e     = (unsigned int*) alloc(HID * 4);
    int*           barv     = (int*)          alloc(8192);

    // mega path never touches h (GEMM result stays in registers); fallback
    // never touches edata4 -> alias edata4 onto h (12.8 MB <= 25.6 MB).
    int4* edata4 = (int4*)h;

    const int NB = (N_NODES + 255) / 256;
    const int EB = (N_EDGES + 255) / 256;
    const size_t NH = (size_t)N_NODES * HID;

    auto kM = k_mega<66, 9, 1536, 3>;
    int occM = 0;
    hipOccupancyMaxActiveBlocksPerMultiprocessor(&occM, kM, 256, 0);

    if (occM >= 3) {
        hipMemsetAsync(barv, 0x00, 8192, stream);
        const int grid = (N_NODES + 65) / 66;          // 758 <= 768
        kM<<<grid, 256, 0, stream>>>(x, spike_node, src, dst, edge_attr, W, b,
                                     counts, cursor, row_ptr, blocksum,
                                     edata4, mn_e, mx_e, sbA, sbB,
                                     out, barv, grid);
        return;
    }

    // ---------- fallback: R2 pipeline ----------
    hipMemsetAsync(counts, 0x00, (size_t)N_NODES * 4, stream);
    hipMemsetAsync(cursor, 0x00, (size_t)N_NODES * 4, stream);
    hipMemsetAsync(mn_e,   0xFF, HID * 4, stream);
    hipMemsetAsync(mx_e,   0x00, HID * 4, stream);
    hipMemsetAsync(barv,   0x00, 8192, stream);

    k_count<<<EB, 256, 0, stream>>>(dst, counts);
    k_scan1<<<NB, 256, 0, stream>>>(counts, row_tmp, blocksum);
    k_scan2<<<1, 64, 0, stream>>>(blocksum, blockoff, NB, row_ptr);
    k_scan3<<<NB, 256, 0, stream>>>(row_tmp, blockoff, row_ptr);
    k_fill<<<EB, 256, 0, stream>>>(dst, src, edge_attr, row_ptr, cursor, eid, edata);
    k_bsort<<<N_NODES / 4, 256, 0, stream>>>(row_ptr, eid, edata);
    k_gemm<<<(N_NODES + 63) / 64, 256, 0, stream>>>(x, W, b, h, mn_e, mx_e);
    k_init_bits<<<NB, 256, 0, stream>>>(spike_node, sbA);

    for (int t = 0; t < T_STEPS; ++t) {
        uint32_t* cur = (t & 1) ? sbB : sbA;
        uint32_t* nxt = (t & 1) ? sbA : sbB;
        k_step<<<N_NODES / 4, 128, 0, stream>>>(row_ptr, edata, cur, nxt,
                                                h, v, refc, mn_e, mx_e,
                                                out + NH + (size_t)t * NH,
                                                out, (t == 0) ? 1 : 0,
                                                (t == T_STEPS - 1) ? 1 : 0);
    }
}

// Round 5
// 621.958 us; speedup vs baseline: 1.0029x; 1.0029x over previous
//
#include <hip/hip_runtime.h>
#include <cstdint>

#define N_NODES 50000
#define N_EDGES 800000
#define IN_DIM  256
#define HID     128
#define T_STEPS 8

#define AG_LOAD(p)     __hip_atomic_load((p), __ATOMIC_RELAXED, __HIP_MEMORY_SCOPE_AGENT)
#define AG_STORE(p, v) __hip_atomic_store((p), (v), __ATOMIC_RELAXED, __HIP_MEMORY_SCOPE_AGENT)
#define AG_ADD(p, v)   __hip_atomic_fetch_add((p), (v), __ATOMIC_RELAXED, __HIP_MEMORY_SCOPE_AGENT)
#define AG_MIN(p, v)   __hip_atomic_fetch_min((p), (v), __ATOMIC_RELAXED, __HIP_MEMORY_SCOPE_AGENT)
#define AG_MAX(p, v)   __hip_atomic_fetch_max((p), (v), __ATOMIC_RELAXED, __HIP_MEMORY_SCOPE_AGENT)

typedef unsigned long long u64;

// ---------- float <-> orderable uint encoding for atomic min/max ----------
static __device__ __forceinline__ unsigned int enc_f(float f) {
    unsigned int u = __float_as_uint(f);
    return (u & 0x80000000u) ? ~u : (u | 0x80000000u);
}
static __device__ __forceinline__ float dec_f(unsigned int u) {
    unsigned int b = (u & 0x80000000u) ? (u ^ 0x80000000u) : ~u;
    return __uint_as_float(b);
}

// ---------- flag-array barrier, ZERO fences / ZERO acq_rel (R2-proven) ----------
// R4 post-mortem: each fbar costs ~19us because __syncthreads (vmcnt(0)) drags
// all pending HBM stores into the barrier critical path. R5 keeps the barrier
// but removes the heavy stores from its path (deferred out-stores, bucket prep).
static __device__ __forceinline__ void fbar(int* bar, int nblk, int t) {
    int* flags = bar;            // [nblk] monotone phase ids
    int* go    = bar + 1900;     // separate line
    __syncthreads();
    if (blockIdx.x == 0) {
        if (threadIdx.x == 0) AG_STORE(&flags[0], t);
        for (;;) {
            int ok = 1;
            for (int i = (int)threadIdx.x; i < nblk; i += 256)
                ok &= (AG_LOAD(&flags[i]) >= t);
            if (__syncthreads_and(ok)) break;
            __builtin_amdgcn_s_sleep(1);
        }
        if (threadIdx.x == 0) AG_STORE(go, t);
    } else {
        if (threadIdx.x == 0) {
            AG_STORE(&flags[blockIdx.x], t);
            while (AG_LOAD(go) < t) __builtin_amdgcn_s_sleep(4);
        }
        __syncthreads();
    }
}

// ================== MEGA2: bucket-prep (1 barrier) + deferred-store LIF ==================
// Prep: scatter edges into per-node fixed buckets (cnt fetch_add + 16B record),
// GEMM into registers + minmax push + spike-init, ONE fbar, then local lrp from
// cnt, per-node bitonic sort (by eid -> np.add.at order) into LDS.
// LIF: 7 fbars; step t's out stores deferred past fbar(t+1) so only the ~1KB
// mask publish sits on each barrier's critical path.
template<int TNPB, int TNSLOT, int TECAP, int TBCAP, int TMINW>
__global__ __launch_bounds__(256, TMINW) void k_mega2(
    const float* __restrict__ x,
    const int*   __restrict__ spike_node,
    const int*   __restrict__ esrc,
    const int*   __restrict__ edst,
    const float* __restrict__ eattr,
    const float* __restrict__ W,
    const float* __restrict__ b,
    int* cnt, int4* bucket,
    unsigned int* mn_e, unsigned int* mx_e,
    uint32_t* sbA, uint32_t* sbB,
    float* __restrict__ out,
    int* bar, int nblk)
{
    __shared__ int      lrp[TNPB + 1];
    __shared__ uint32_t pool[TECAP * 6];
    __shared__ uint32_t sbw[TNPB][4];

    int*      ed_src_l  = (int*)pool;                 // [TECAP]   steady
    float*    ed_attr_l = (float*)(pool + TECAP);     // [TECAP]   steady
    uint32_t* ed_wds    = pool + 2 * TECAP;           // [TECAP*4] step loop / sort keys
    float*    Ws        = (float*)pool;               // [4096]  gemm (transient)
    float*    xs        = (float*)(pool + 4096);      // [TNPB*36] gemm (transient)
    float*    red_mn    = (float*)pool;               // [1024] minmax (transient)
    float*    red_mx    = (float*)(pool + 1024);      // [1024]
    int*      cnt_l     = (int*)sbw;                  // [TNPB] (transient, pre-zero)

    const int tid = threadIdx.x;
    const int bid = blockIdx.x;
    const int g   = tid >> 5, ln = tid & 31;
    const int n0  = bid * TNPB;
    const int ncnt = min(TNPB, N_NODES - n0);
    const int w = ln >> 3, shb = (ln & 7) * 4;
    const size_t NH = (size_t)N_NODES * HID;

    // ---- P0: spike-bit init (own nodes) ----
    for (int i = tid; i < ncnt; i += 256) {
        uint32_t f = spike_node[n0 + i] ? 0xFFFFFFFFu : 0u;
        u64 ff = (u64)f | ((u64)f << 32);
        AG_STORE((u64*)&sbA[(size_t)(n0 + i) * 4], ff);
        AG_STORE((u64*)&sbA[(size_t)(n0 + i) * 4 + 2], ff);
    }

    // ---- P1: bucket fill (cnt host-zeroed). 1 RMW + one 16B record per edge ----
    for (int e = bid * 256 + tid; e < N_EDGES; e += nblk * 256) {
        int d = edst[e];
        int p = AG_ADD(&cnt[d], 1);
        if (p < TBCAP) {
            u64* qp = (u64*)&bucket[(size_t)d * TBCAP + p];
            u64 a  = (u64)(unsigned int)e | ((u64)(unsigned int)esrc[e] << 32);
            u64 bq = (u64)__float_as_uint(eattr[e]);
            AG_STORE(qp, a);
            AG_STORE(qp + 1, bq);
        }
    }

    // ---- P2: GEMM into registers (bit-identical FMA sequence) ----
    float4 hs[TNSLOT], vs[TNSLOT];
    uint32_t rcs[TNSLOT], nibs[TNSLOT];
    #pragma unroll
    for (int s = 0; s < TNSLOT; ++s) hs[s] = make_float4(0.f, 0.f, 0.f, 0.f);
    int xoff[TNSLOT];
    #pragma unroll
    for (int s = 0; s < TNSLOT; ++s) xoff[s] = min(s * 8 + g, TNPB - 1) * 36;

    for (int kc = 0; kc < IN_DIM; kc += 32) {
        __syncthreads();
        for (int idx = tid; idx < TNPB * 8; idx += 256) {
            int node = idx >> 3, q = idx & 7;
            int row = min(n0 + node, N_NODES - 1);
            *(float4*)&xs[node * 36 + q * 4] =
                *(const float4*)(x + (size_t)row * IN_DIM + kc + q * 4);
        }
        for (int idx = tid; idx < 1024; idx += 256) {
            int r = idx >> 5, c = idx & 31;
            *(float4*)&Ws[r * 128 + c * 4] =
                *(const float4*)(W + (size_t)(kc + r) * HID + c * 4);
        }
        __syncthreads();
        #pragma unroll 4
        for (int k = 0; k < 32; ++k) {
            float4 wf = *(float4*)&Ws[k * 128 + ln * 4];
            #pragma unroll
            for (int s = 0; s < TNSLOT; ++s) {
                float xv = xs[xoff[s] + k];
                hs[s].x = __fmaf_rn(xv, wf.x, hs[s].x);
                hs[s].y = __fmaf_rn(xv, wf.y, hs[s].y);
                hs[s].z = __fmaf_rn(xv, wf.z, hs[s].z);
                hs[s].w = __fmaf_rn(xv, wf.w, hs[s].w);
            }
        }
    }
    {   // bias + per-feature minmax reduce + global push
        float4 bv = *(const float4*)(b + ln * 4);
        float lmn[4], lmx[4];
        #pragma unroll
        for (int c = 0; c < 4; ++c) { lmn[c] = INFINITY; lmx[c] = -INFINITY; }
        #pragma unroll
        for (int s = 0; s < TNSLOT; ++s) {
            hs[s].x = __fadd_rn(hs[s].x, bv.x);
            hs[s].y = __fadd_rn(hs[s].y, bv.y);
            hs[s].z = __fadd_rn(hs[s].z, bv.z);
            hs[s].w = __fadd_rn(hs[s].w, bv.w);
            lmn[0] = fminf(lmn[0], hs[s].x); lmx[0] = fmaxf(lmx[0], hs[s].x);
            lmn[1] = fminf(lmn[1], hs[s].y); lmx[1] = fmaxf(lmx[1], hs[s].y);
            lmn[2] = fminf(lmn[2], hs[s].z); lmx[2] = fmaxf(lmx[2], hs[s].z);
            lmn[3] = fminf(lmn[3], hs[s].w); lmx[3] = fmaxf(lmx[3], hs[s].w);
        }
        __syncthreads();                       // Ws/xs dead
        #pragma unroll
        for (int c = 0; c < 4; ++c) {
            red_mn[g * 128 + ln * 4 + c] = lmn[c];
            red_mx[g * 128 + ln * 4 + c] = lmx[c];
        }
        __syncthreads();
        if (tid < 128) {
            float mnv = red_mn[tid], mxv = red_mx[tid];
            #pragma unroll
            for (int r = 1; r < 8; ++r) {
                mnv = fminf(mnv, red_mn[r * 128 + tid]);
                mxv = fmaxf(mxv, red_mx[r * 128 + tid]);
            }
            AG_MIN(&mn_e[tid], enc_f(mnv));
            AG_MAX(&mx_e[tid], enc_f(mxv));
        }
        __syncthreads();                       // red dead
    }

    // ======== THE single prep barrier: fill + minmax + sbA all visible ========
    fbar(bar, nblk, 1);

    // ---- P3: local lrp from cnt (no global coordination needed) ----
    if (tid < ncnt) cnt_l[tid] = min(AG_LOAD(&cnt[n0 + tid]), TBCAP);
    __syncthreads();
    if (tid == 0) {
        int run = 0;
        for (int i = 0; i < ncnt; ++i) { lrp[i] = run; run += cnt_l[i]; }
        lrp[ncnt] = run;
    }
    __syncthreads();
    const int etot  = lrp[ncnt];
    const bool inlds = (etot <= TECAP);

    // ---- normalize hs ----
    {
        float mn0 = dec_f(AG_LOAD(&mn_e[ln * 4 + 0]));
        float mn1 = dec_f(AG_LOAD(&mn_e[ln * 4 + 1]));
        float mn2 = dec_f(AG_LOAD(&mn_e[ln * 4 + 2]));
        float mn3 = dec_f(AG_LOAD(&mn_e[ln * 4 + 3]));
        float dd0 = __fadd_rn(__fsub_rn(dec_f(AG_LOAD(&mx_e[ln * 4 + 0])), mn0), 1e-6f);
        float dd1 = __fadd_rn(__fsub_rn(dec_f(AG_LOAD(&mx_e[ln * 4 + 1])), mn1), 1e-6f);
        float dd2 = __fadd_rn(__fsub_rn(dec_f(AG_LOAD(&mx_e[ln * 4 + 2])), mn2), 1e-6f);
        float dd3 = __fadd_rn(__fsub_rn(dec_f(AG_LOAD(&mx_e[ln * 4 + 3])), mn3), 1e-6f);
        #pragma unroll
        for (int s = 0; s < TNSLOT; ++s) {
            hs[s].x = __fdiv_rn(__fsub_rn(hs[s].x, mn0), dd0);
            hs[s].y = __fdiv_rn(__fsub_rn(hs[s].y, mn1), dd1);
            hs[s].z = __fdiv_rn(__fsub_rn(hs[s].z, mn2), dd2);
            hs[s].w = __fdiv_rn(__fsub_rn(hs[s].w, mn3), dd3);
        }
    }
    #pragma unroll
    for (int s = 0; s < TNSLOT; ++s) { vs[s] = make_float4(0.f,0.f,0.f,0.f); rcs[s] = 0u; }

    // ---- P4: per-node sort by eid (np.add.at ascending order) ----
    if (inlds) {
        for (int m = tid >> 6; m < ncnt; m += 4) {
            int l = tid & 63;
            int lbeg = lrp[m];
            int c = lrp[m + 1] - lbeg;
            if (c <= 0) continue;
            const u64* brow = (const u64*)&bucket[(size_t)(n0 + m) * TBCAP];
            if (c <= 64) {
                int key = 0x7FFFFFFF, sv = 0, av = 0;
                if (l < c) {
                    u64 a  = AG_LOAD(brow + 2 * l);
                    u64 bq = AG_LOAD(brow + 2 * l + 1);
                    key = (int)(unsigned int)a;
                    sv  = (int)(unsigned int)(a >> 32);
                    av  = (int)(unsigned int)bq;
                }
                #pragma unroll
                for (int k = 2; k <= 64; k <<= 1) {
                    for (int j = k >> 1; j > 0; j >>= 1) {
                        int pk2 = __shfl_xor(key, j);
                        int ps  = __shfl_xor(sv, j);
                        int pa  = __shfl_xor(av, j);
                        bool lower = (l & j) == 0;
                        bool asc   = (l & k) == 0;
                        bool take  = (lower == asc) ? (pk2 < key) : (pk2 > key);
                        if (take) { key = pk2; sv = ps; av = pa; }
                    }
                }
                if (l < c) {
                    ed_src_l[lbeg + l]  = sv;
                    ed_attr_l[lbeg + l] = __int_as_float(av);
                }
            } else if (l == 0) {   // robustness path (64 < c <= TBCAP); dead here
                for (int i = 0; i < c; ++i) {
                    u64 a  = AG_LOAD(brow + 2 * i);
                    u64 bq = AG_LOAD(brow + 2 * i + 1);
                    int ke  = (int)(unsigned int)a;
                    int svv = (int)(unsigned int)(a >> 32);
                    int avv = (int)(unsigned int)bq;
                    int mm = i - 1;
                    while (mm >= 0 && (int)ed_wds[lbeg + mm] > ke) {
                        ed_wds[lbeg + mm + 1]    = ed_wds[lbeg + mm];
                        ed_src_l[lbeg + mm + 1]  = ed_src_l[lbeg + mm];
                        ed_attr_l[lbeg + mm + 1] = ed_attr_l[lbeg + mm];
                        --mm;
                    }
                    ed_wds[lbeg + mm + 1]    = (uint32_t)ke;
                    ed_src_l[lbeg + mm + 1]  = svv;
                    ed_attr_l[lbeg + mm + 1] = __int_as_float(avv);
                }
            }
        }
    } else {            // overflow: sort buckets in place (dead for this input)
        for (int m = tid >> 6; m < ncnt; m += 4) {
            int l = tid & 63;
            int c = lrp[m + 1] - lrp[m];
            if (c <= 1) continue;
            u64* brow = (u64*)&bucket[(size_t)(n0 + m) * TBCAP];
            if (c <= 64) {
                int key = 0x7FFFFFFF, sv = 0, av = 0;
                if (l < c) {
                    u64 a  = AG_LOAD(brow + 2 * l);
                    u64 bq = AG_LOAD(brow + 2 * l + 1);
                    key = (int)(unsigned int)a;
                    sv  = (int)(unsigned int)(a >> 32);
                    av  = (int)(unsigned int)bq;
                }
                #pragma unroll
                for (int k = 2; k <= 64; k <<= 1) {
                    for (int j = k >> 1; j > 0; j >>= 1) {
                        int pk2 = __shfl_xor(key, j);
                        int ps  = __shfl_xor(sv, j);
                        int pa  = __shfl_xor(av, j);
                        bool lower = (l & j) == 0;
                        bool asc   = (l & k) == 0;
                        bool take  = (lower == asc) ? (pk2 < key) : (pk2 > key);
                        if (take) { key = pk2; sv = ps; av = pa; }
                    }
                }
                if (l < c) {
                    u64 a = (u64)(unsigned int)key | ((u64)(unsigned int)sv << 32);
                    AG_STORE(brow + 2 * l, a);
                    AG_STORE(brow + 2 * l + 1, (u64)(unsigned int)av);
                }
            } else if (l == 0) {
                for (int i = 1; i < c; ++i) {
                    u64 ka = AG_LOAD(brow + 2 * i);
                    u64 kb = AG_LOAD(brow + 2 * i + 1);
                    int ke = (int)(unsigned int)ka;
                    int mm = i - 1;
                    while (mm >= 0) {
                        u64 ma = AG_LOAD(brow + 2 * mm);
                        if ((int)(unsigned int)ma <= ke) break;
                        AG_STORE(brow + 2 * mm + 2, ma);
                        AG_STORE(brow + 2 * mm + 3, AG_LOAD(brow + 2 * mm + 1));
                        --mm;
                    }
                    AG_STORE(brow + 2 * mm + 2, ka);
                    AG_STORE(brow + 2 * mm + 3, kb);
                }
            }
        }
    }
    __syncthreads();                 // cnt_l (sbw) dead; sort complete locally
    for (int i = tid; i < ncnt * 2; i += 256) ((u64*)sbw)[i] = 0ull;

    // ---- 8-step LIF with deferred out stores ----
    for (int t = 0; t < T_STEPS; ++t) {
        const uint32_t* cur = (t & 1) ? sbB : sbA;
        uint32_t*       nxt = (t & 1) ? sbA : sbB;
        if (t > 0) {
            fbar(bar, nblk, 1 + t);            // only ~1KB publish on its path
            #pragma unroll
            for (int s = 0; s < TNSLOT; ++s) { // deferred: step t-1 spikes
                int m = s * 8 + g;
                if (m < ncnt) {
                    uint32_t nb4 = nibs[s];
                    size_t idx = (size_t)(n0 + m) * HID + ln * 4;
                    *(float4*)&out[NH + (size_t)(t - 1) * NH + idx] = make_float4(
                        (nb4 & 1u) ? 1.0f : 0.0f, (nb4 & 2u) ? 1.0f : 0.0f,
                        (nb4 & 4u) ? 1.0f : 0.0f, (nb4 & 8u) ? 1.0f : 0.0f);
                }
            }
        }

        if (inlds) {                          // stage this step's spike words
            for (int i = tid; i < etot; i += 256) {
                u64* sp = (u64*)&cur[(size_t)ed_src_l[i] * 4];
                u64 lo = AG_LOAD(sp);
                u64 hi = AG_LOAD(sp + 1);
                uint4 wv;
                wv.x = (uint32_t)lo; wv.y = (uint32_t)(lo >> 32);
                wv.z = (uint32_t)hi; wv.w = (uint32_t)(hi >> 32);
                *(uint4*)&ed_wds[i * 4] = wv;
            }
        }
        __syncthreads();                      // drains staging + deferred stores

        #pragma unroll
        for (int s = 0; s < TNSLOT; ++s) {
            int m = s * 8 + g;
            if (m < ncnt) {
                float ag0 = 0.f, ag1 = 0.f, ag2 = 0.f, ag3 = 0.f;
                if (inlds) {
                    int lb = lrp[m], le = lrp[m + 1];
                    for (int i = lb; i < le; ++i) {       // ascending eid order
                        uint32_t u = ed_wds[i * 4 + w];
                        float a = ed_attr_l[i];
                        uint32_t bits = (u >> shb) & 0xFu;
                        ag0 = __fadd_rn(ag0, (bits & 1u) ? a : 0.f);
                        ag1 = __fadd_rn(ag1, (bits & 2u) ? a : 0.f);
                        ag2 = __fadd_rn(ag2, (bits & 4u) ? a : 0.f);
                        ag3 = __fadd_rn(ag3, (bits & 8u) ? a : 0.f);
                    }
                } else {                                  // overflow fallback
                    int c = lrp[m + 1] - lrp[m];
                    const u64* brow = (const u64*)&bucket[(size_t)(n0 + m) * TBCAP];
                    for (int i = 0; i < c; ++i) {
                        u64 a  = AG_LOAD(brow + 2 * i);
                        u64 bq = AG_LOAD(brow + 2 * i + 1);
                        int srcn = (int)(unsigned int)(a >> 32);
                        float av = __uint_as_float((unsigned int)bq);
                        uint32_t u = AG_LOAD((uint32_t*)&cur[(size_t)srcn * 4 + w]);
                        uint32_t bits = (u >> shb) & 0xFu;
                        ag0 = __fadd_rn(ag0, (bits & 1u) ? av : 0.f);
                        ag1 = __fadd_rn(ag1, (bits & 2u) ? av : 0.f);
                        ag2 = __fadd_rn(ag2, (bits & 4u) ? av : 0.f);
                        ag3 = __fadd_rn(ag3, (bits & 8u) ? av : 0.f);
                    }
                }

                // LIF update (identical FP sequence to reference)
                float hv[4] = {hs[s].x, hs[s].y, hs[s].z, hs[s].w};
                float vv[4] = {vs[s].x, vs[s].y, vs[s].z, vs[s].w};
                float ag[4] = {ag0, ag1, ag2, ag3};
                float vf[4];
                uint32_t rcu = rcs[s], rcn = 0u, nib = 0u;
                #pragma unroll
                for (int q = 0; q < 4; ++q) {
                    float vn = __fadd_rn(__fadd_rn(__fmul_rn(0.8f, vv[q]), hv[q]), ag[q]);
                    uint32_t rc = (rcu >> (8 * q)) & 0xFFu;
                    bool spk = (vn >= 0.5f) && (rc == 0u);
                    vf[q] = spk ? 0.0f : vn;
                    uint32_t rnew = spk ? 2u : (rc > 0u ? rc - 1u : 0u);
                    rcn |= rnew << (8 * q);
                    nib |= (spk ? 1u : 0u) << q;
                }
                vs[s] = make_float4(vf[0], vf[1], vf[2], vf[3]);
                rcs[s] = rcn;
                nibs[s] = nib;                // out store deferred past fbar(t+1)
                atomicOr(&sbw[m][w], nib << shb);
            }
        }
        __syncthreads();
        for (int i = tid; i < ncnt * 2; i += 256) {   // publish (LLC) + re-zero
            AG_STORE((u64*)&nxt[(size_t)n0 * 4] + i, ((u64*)sbw)[i]);
            ((u64*)sbw)[i] = 0ull;
        }
    }

    // ---- final: step 7 spikes + fusion (no barrier needed) ----
    #pragma unroll
    for (int s = 0; s < TNSLOT; ++s) {
        int m = s * 8 + g;
        if (m < ncnt) {
            uint32_t nb4 = nibs[s];
            size_t idx = (size_t)(n0 + m) * HID + ln * 4;
            *(float4*)&out[NH + (size_t)(T_STEPS - 1) * NH + idx] = make_float4(
                (nb4 & 1u) ? 1.0f : 0.0f, (nb4 & 2u) ? 1.0f : 0.0f,
                (nb4 & 4u) ? 1.0f : 0.0f, (nb4 & 8u) ? 1.0f : 0.0f);
            *(float4*)&out[idx] = make_float4(
                __fadd_rn(hs[s].x, __fmul_rn(0.5f, vs[s].x)),
                __fadd_rn(hs[s].y, __fmul_rn(0.5f, vs[s].y)),
                __fadd_rn(hs[s].z, __fmul_rn(0.5f, vs[s].z)),
                __fadd_rn(hs[s].w, __fmul_rn(0.5f, vs[s].w)));
        }
    }
}

// ================== fallback pipeline (unchanged, R2-proven) ==================
__global__ void k_count(const int* __restrict__ dst, int* __restrict__ counts) {
    int e = blockIdx.x * blockDim.x + threadIdx.x;
    if (e < N_EDGES) atomicAdd(&counts[dst[e]], 1);
}

__global__ void k_scan1(const int* __restrict__ counts, int* __restrict__ row_tmp,
                        int* __restrict__ blocksum) {
    __shared__ int sh[256];
    int t = threadIdx.x, i = blockIdx.x * 256 + t;
    int c = (i < N_NODES) ? counts[i] : 0;
    sh[t] = c; __syncthreads();
    for (int off = 1; off < 256; off <<= 1) {
        int val = (t >= off) ? sh[t - off] : 0;
        __syncthreads();
        sh[t] += val;
        __syncthreads();
    }
    if (i < N_NODES) row_tmp[i] = sh[t] - c;
    if (t == 255) blocksum[blockIdx.x] = sh[255];
}

__global__ void k_scan2(const int* __restrict__ blocksum, int* __restrict__ blockoff,
                        int nb, int* __restrict__ row_ptr) {
    if (threadIdx.x == 0) {
        int acc = 0;
        for (int b = 0; b < nb; ++b) { blockoff[b] = acc; acc += blocksum[b]; }
        row_ptr[N_NODES] = acc;
    }
}

__global__ void k_scan3(const int* __restrict__ row_tmp, const int* __restrict__ blockoff,
                        int* __restrict__ row_ptr) {
    int i = blockIdx.x * blockDim.x + threadIdx.x;
    if (i < N_NODES) row_ptr[i] = row_tmp[i] + blockoff[i >> 8];
}

__global__ void k_fill(const int* __restrict__ dst, const int* __restrict__ src,
                       const float* __restrict__ attr,
                       const int* __restrict__ row_ptr, int* __restrict__ cursor,
                       int* __restrict__ eid, int2* __restrict__ edata) {
    int e = blockIdx.x * blockDim.x + threadIdx.x;
    if (e >= N_EDGES) return;
    int d = dst[e];
    int p = row_ptr[d] + atomicAdd(&cursor[d], 1);
    eid[p]   = e;
    edata[p] = make_int2(src[e], __float_as_int(attr[e]));
}

__global__ __launch_bounds__(256) void k_bsort(const int* __restrict__ row_ptr,
                                               int* __restrict__ eid,
                                               int2* __restrict__ edata) {
    int node = blockIdx.x * 4 + (threadIdx.x >> 6);
    int l = threadIdx.x & 63;
    int beg = row_ptr[node], end = row_ptr[node + 1], cnt = end - beg;
    if (cnt <= 1) return;
    if (cnt <= 64) {
        int key = 0x7FFFFFFF, sv = 0, av = 0;
        if (l < cnt) { key = eid[beg + l]; int2 d = edata[beg + l]; sv = d.x; av = d.y; }
        #pragma unroll
        for (int k = 2; k <= 64; k <<= 1) {
            for (int j = k >> 1; j > 0; j >>= 1) {
                int pk = __shfl_xor(key, j);
                int ps = __shfl_xor(sv, j);
                int pa = __shfl_xor(av, j);
                bool lower = (l & j) == 0;
                bool asc   = (l & k) == 0;
                bool take = ((lower == asc)) ? (pk < key) : (pk > key);
                if (take) { key = pk; sv = ps; av = pa; }
            }
        }
        if (l < cnt) { eid[beg + l] = key; edata[beg + l] = make_int2(sv, av); }
    } else if (l == 0) {
        for (int i = beg + 1; i < end; ++i) {
            int ke = eid[i]; int2 kd = edata[i];
            int m = i - 1;
            while (m >= beg && eid[m] > ke) {
                eid[m+1] = eid[m]; edata[m+1] = edata[m]; --m;
            }
            eid[m+1] = ke; edata[m+1] = kd;
        }
    }
}

__global__ __launch_bounds__(256) void k_gemm(const float* __restrict__ x,
                                              const float* __restrict__ W,
                                              const float* __restrict__ b,
                                              float* __restrict__ h,
                                              unsigned int* __restrict__ mn_e,
                                              unsigned int* __restrict__ mx_e) {
    __shared__ float Ws[32 * 128];
    __shared__ float xs[64 * 36];
    __shared__ float red_mn[8 * 128];
    __shared__ float red_mx[8 * 128];
    const int tid = threadIdx.x;
    const int n0 = blockIdx.x * 64;
    const int jt = tid & 31, nt = tid >> 5;
    const int j0 = jt * 4;

    float acc[8][4];
    #pragma unroll
    for (int a = 0; a < 8; ++a)
        #pragma unroll
        for (int c = 0; c < 4; ++c) acc[a][c] = 0.0f;

    const int ldn = tid >> 2;
    const int kq  = (tid & 3) * 8;
    const int xrow = (n0 + ldn < N_NODES) ? (n0 + ldn) : (N_NODES - 1);
    const float* xg = x + (size_t)xrow * IN_DIM;

    for (int kc = 0; kc < IN_DIM; kc += 32) {
        __syncthreads();
        float4 xa = *(const float4*)(xg + kc + kq);
        float4 xb = *(const float4*)(xg + kc + kq + 4);
        *(float4*)&xs[ldn * 36 + kq]     = xa;
        *(float4*)&xs[ldn * 36 + kq + 4] = xb;
        #pragma unroll
        for (int p = 0; p < 4; ++p) {
            int r = nt + p * 8;
            *(float4*)&Ws[r * 128 + j0] =
                *(const float4*)(W + (size_t)(kc + r) * HID + j0);
        }
        __syncthreads();
        const float* xbase = &xs[nt * 8 * 36];
        #pragma unroll 4
        for (int k = 0; k < 32; ++k) {
            float4 wf = *(const float4*)&Ws[k * 128 + j0];
            #pragma unroll
            for (int ni = 0; ni < 8; ++ni) {
                float xv = xbase[ni * 36 + k];
                acc[ni][0] = __fmaf_rn(xv, wf.x, acc[ni][0]);
                acc[ni][1] = __fmaf_rn(xv, wf.y, acc[ni][1]);
                acc[ni][2] = __fmaf_rn(xv, wf.z, acc[ni][2]);
                acc[ni][3] = __fmaf_rn(xv, wf.w, acc[ni][3]);
            }
        }
    }

    float4 bv = *(const float4*)(b + j0);
    float lmn[4], lmx[4];
    #pragma unroll
    for (int c = 0; c < 4; ++c) { lmn[c] = INFINITY; lmx[c] = -INFINITY; }
    #pragma unroll
    for (int ni = 0; ni < 8; ++ni) {
        acc[ni][0] = __fadd_rn(acc[ni][0], bv.x);
        acc[ni][1] = __fadd_rn(acc[ni][1], bv.y);
        acc[ni][2] = __fadd_rn(acc[ni][2], bv.z);
        acc[ni][3] = __fadd_rn(acc[ni][3], bv.w);
        #pragma unroll
        for (int c = 0; c < 4; ++c) {
            lmn[c] = fminf(lmn[c], acc[ni][c]);
            lmx[c] = fmaxf(lmx[c], acc[ni][c]);
        }
    }
    #pragma unroll
    for (int c = 0; c < 4; ++c) {
        red_mn[nt * 128 + j0 + c] = lmn[c];
        red_mx[nt * 128 + j0 + c] = lmx[c];
    }
    __syncthreads();
    if (tid < 128) {
        float mnv = red_mn[tid], mxv = red_mx[tid];
        #pragma unroll
        for (int r = 1; r < 8; ++r) {
            mnv = fminf(mnv, red_mn[r * 128 + tid]);
            mxv = fmaxf(mxv, red_mx[r * 128 + tid]);
        }
        atomicMin(&mn_e[tid], enc_f(mnv));
        atomicMax(&mx_e[tid], enc_f(mxv));
    }
    #pragma unroll
    for (int ni = 0; ni < 8; ++ni) {
        int n = n0 + nt * 8 + ni;
        if (n < N_NODES)
            *(float4*)&h[(size_t)n * HID + j0] =
                make_float4(acc[ni][0], acc[ni][1], acc[ni][2], acc[ni][3]);
    }
}

__global__ void k_init_bits(const int* __restrict__ spike_node, uint32_t* __restrict__ sb) {
    int n = blockIdx.x * blockDim.x + threadIdx.x;
    if (n >= N_NODES) return;
    uint32_t f = spike_node[n] ? 0xFFFFFFFFu : 0u;
    sb[(size_t)n * 4 + 0] = f;
    sb[(size_t)n * 4 + 1] = f;
    sb[(size_t)n * 4 + 2] = f;
    sb[(size_t)n * 4 + 3] = f;
}

__global__ __launch_bounds__(128) void k_step(const int* __restrict__ row_ptr,
                                              const int2* __restrict__ edata,
                                              const uint32_t* __restrict__ sb_cur,
                                              uint32_t* __restrict__ sb_nxt,
                                              float* __restrict__ h,
                                              float* __restrict__ v,
                                              unsigned char* __restrict__ refc,
                                              const unsigned int* __restrict__ mn_e,
                                              const unsigned int* __restrict__ mx_e,
                                              float* __restrict__ out_spk,
                                              float* __restrict__ out_fus,
                                              int t0, int is_last) {
    __shared__ float    attr_l[4][128];
    __shared__ uint32_t words_l[4][128][4];
    __shared__ uint32_t sbw[16];
    __shared__ int      rp[5];

    const int tid = threadIdx.x;
    const int ns = tid >> 5, ln = tid & 31;
    const int nb = blockIdx.x * 4;
    const int n  = nb + ns;

    if (tid < 16) sbw[tid] = 0;
    if (tid < 5)  rp[tid] = row_ptr[nb + tid];
    __syncthreads();

    const int beg = rp[ns], cnt = rp[ns + 1] - beg;
    int cmax = 0;
    #pragma unroll
    for (int q = 0; q < 4; ++q) cmax = max(cmax, rp[q + 1] - rp[q]);
    const int nchunk = (cmax + 127) >> 7;

    float agg0 = 0.f, agg1 = 0.f, agg2 = 0.f, agg3 = 0.f;
    const int w = ln >> 3, shb = (ln & 7) * 4;

    for (int ch = 0; ch < nchunk; ++ch) {
        int base = ch << 7;
        __syncthreads();
        #pragma unroll
        for (int rep = 0; rep < 4; ++rep) {
            int i = base + rep * 32 + ln;
            if (i < cnt) {
                int2 d = edata[beg + i];
                attr_l[ns][rep * 32 + ln] = __int_as_float(d.y);
                *(uint4*)&words_l[ns][rep * 32 + ln][0] =
                    *(const uint4*)&sb_cur[(size_t)d.x * 4];
            }
        }
        __syncthreads();
        int lim = min(128, cnt - base);
        for (int i = 0; i < lim; ++i) {
            uint32_t u = words_l[ns][i][w];
            float a = attr_l[ns][i];
            uint32_t bits = (u >> shb) & 0xFu;
            agg0 = __fadd_rn(agg0, (bits & 1u) ? a : 0.0f);
            agg1 = __fadd_rn(agg1, (bits & 2u) ? a : 0.0f);
            agg2 = __fadd_rn(agg2, (bits & 4u) ? a : 0.0f);
            agg3 = __fadd_rn(agg3, (bits & 8u) ? a : 0.0f);
        }
    }

    const size_t idx = (size_t)n * HID + ln * 4;
    float4 h4 = *(const float4*)&h[idx];
    if (t0) {
        const int jb = ln * 4;
        float hq[4] = {h4.x, h4.y, h4.z, h4.w};
        #pragma unroll
        for (int q = 0; q < 4; ++q) {
            float mn = dec_f(mn_e[jb + q]);
            float mx = dec_f(mx_e[jb + q]);
            float d2 = __fadd_rn(__fsub_rn(mx, mn), 1e-6f);
            hq[q] = __fdiv_rn(__fsub_rn(hq[q], mn), d2);
        }
        h4 = make_float4(hq[0], hq[1], hq[2], hq[3]);
        *(float4*)&h[idx] = h4;
    }
    float4 v4;
    unsigned int rcu;
    if (t0) { v4 = make_float4(0.f, 0.f, 0.f, 0.f); rcu = 0u; }
    else    { v4 = *(const float4*)&v[idx]; rcu = *(const unsigned int*)&refc[idx]; }

    float hv[4]  = {h4.x, h4.y, h4.z, h4.w};
    float vv[4]  = {v4.x, v4.y, v4.z, v4.w};
    float ag[4]  = {agg0, agg1, agg2, agg3};
    float vf[4], sf[4];
    unsigned int rcn = 0u, nib = 0u;
    #pragma unroll
    for (int q = 0; q < 4; ++q) {
        float vn = __fadd_rn(__fadd_rn(__fmul_rn(0.8f, vv[q]), hv[q]), ag[q]);
        unsigned int rc = (rcu >> (8 * q)) & 0xFFu;
        bool spk = (vn >= 0.5f) && (rc == 0u);
        vf[q] = spk ? 0.0f : vn;
        sf[q] = spk ? 1.0f : 0.0f;
        unsigned int rnew = spk ? 2u : (rc > 0u ? rc - 1u : 0u);
        rcn |= rnew << (8 * q);
        nib |= (spk ? 1u : 0u) << q;
    }
    *(float4*)&v[idx] = make_float4(vf[0], vf[1], vf[2], vf[3]);
    *(unsigned int*)&refc[idx] = rcn;
    *(float4*)&out_spk[idx] = make_float4(sf[0], sf[1], sf[2], sf[3]);
    if (is_last) {
        *(float4*)&out_fus[idx] = make_float4(
            __fadd_rn(hv[0], __fmul_rn(0.5f, vf[0])),
            __fadd_rn(hv[1], __fmul_rn(0.5f, vf[1])),
            __fadd_rn(hv[2], __fmul_rn(0.5f, vf[2])),
            __fadd_rn(hv[3], __fmul_rn(0.5f, vf[3])));
    }
    atomicOr(&sbw[ns * 4 + w], nib << shb);
    __syncthreads();
    if (tid < 16)
        sb_nxt[(size_t)(nb + (tid >> 2)) * 4 + (tid & 3)] = sbw[tid];
}

extern "C" void kernel_launch(void* const* d_in, const int* in_sizes, int n_in,
                              void* d_out, int out_size, void* d_ws, size_t ws_size,
                              hipStream_t stream) {
    const float* x          = (const float*)d_in[0];
    const int*   spike_node = (const int*)  d_in[1];
    const int*   edge_index = (const int*)  d_in[2];   // [2][E]
    const float* edge_attr  = (const float*)d_in[4];
    const float* W          = (const float*)d_in[5];
    const float* b          = (const float*)d_in[6];
    float* out = (float*)d_out;

    const int* src = edge_index;
    const int* dst = edge_index + N_EDGES;

    char* wsp = (char*)d_ws;
    auto alloc = [&](size_t bytes) {
        char* p = wsp;
        wsp += (bytes + 255) & ~(size_t)255;
        return p;
    };

    const int NB = (N_NODES + 255) / 256;
    const int EB = (N_EDGES + 255) / 256;
    const size_t NH = (size_t)N_NODES * HID;
    const int BCAP = 80;

    auto kM = k_mega2<66, 9, 1536, 80, 3>;
    int occM = 0;
    hipOccupancyMaxActiveBlocksPerMultiprocessor(&occM, kM, 256, 0);

    if (occM >= 3) {
        // mega layout: bucket first (64 MB), then small state
        int4*         bucket = (int4*)        alloc((size_t)N_NODES * BCAP * 16);
        int*          cnt    = (int*)         alloc((size_t)N_NODES * 4);
        uint32_t*     sbA    = (uint32_t*)    alloc((size_t)N_NODES * 16);
        uint32_t*     sbB    = (uint32_t*)    alloc((size_t)N_NODES * 16);
        unsigned int* mn_e   = (unsigned int*)alloc(HID * 4);
        unsigned int* mx_e   = (unsigned int*)alloc(HID * 4);
        int*          barv   = (int*)         alloc(8192);

        hipMemsetAsync(cnt,  0x00, (size_t)N_NODES * 4, stream);
        hipMemsetAsync(mn_e, 0xFF, HID * 4, stream);
        hipMemsetAsync(mx_e, 0x00, HID * 4, stream);
        hipMemsetAsync(barv, 0x00, 8192, stream);

        const int grid = (N_NODES + 65) / 66;          // 758 <= 768
        kM<<<grid, 256, 0, stream>>>(x, spike_node, src, dst, edge_attr, W, b,
                                     cnt, bucket, mn_e, mx_e, sbA, sbB,
                                     out, barv, grid);
        return;
    }

    // ---------- fallback: R2 pipeline ----------
    float*         h        = (float*)        alloc((size_t)N_NODES * HID * 4);
    float*         v        = (float*)        alloc((size_t)N_NODES * HID * 4);
    unsigned char* refc     = (unsigned char*)alloc((size_t)N_NODES * HID);
    uint32_t*      sbA      = (uint32_t*)     alloc((size_t)N_NODES * 16);
    uint32_t*      sbB      = (uint32_t*)     alloc((size_t)N_NODES * 16);
    int*           counts   = (int*)          alloc((size_t)N_NODES * 4);
    int*           cursor   = (int*)          alloc((size_t)N_NODES * 4);
    int*           row_tmp  = (int*)          alloc((size_t)N_NODES * 4);
    int*           row_ptr  = (int*)          alloc((size_t)(N_NODES + 1) * 4);
    int*           blocksum = (int*)          alloc(1024 * 4);
    int*           blockoff = (int*)          alloc(1024 * 4);
    int*           eid      = (int*)          alloc((size_t)N_EDGES * 4);
    int2*          edata    = (int2*)         alloc((size_t)N_EDGES * 8);
    unsigned int*  mn_e     = (unsigned int*) alloc(HID * 4);
    unsigned int*  mx_e     = (unsigned int*) alloc(HID * 4);

    hipMemsetAsync(counts, 0x00, (size_t)N_NODES * 4, stream);
    hipMemsetAsync(cursor, 0x00, (size_t)N_NODES * 4, stream);
    hipMemsetAsync(mn_e,   0xFF, HID * 4, stream);
    hipMemsetAsync(mx_e,   0x00, HID * 4, stream);

    k_count<<<EB, 256, 0, stream>>>(dst, counts);
    k_scan1<<<NB, 256, 0, stream>>>(counts, row_tmp, blocksum);
    k_scan2<<<1, 64, 0, stream>>>(blocksum, blockoff, NB, row_ptr);
    k_scan3<<<NB, 256, 0, stream>>>(row_tmp, blockoff, row_ptr);
    k_fill<<<EB, 256, 0, stream>>>(dst, src, edge_attr, row_ptr, cursor, eid, edata);
    k_bsort<<<N_NODES / 4, 256, 0, stream>>>(row_ptr, eid, edata);
    k_gemm<<<(N_NODES + 63) / 64, 256, 0, stream>>>(x, W, b, h, mn_e, mx_e);
    k_init_bits<<<NB, 256, 0, stream>>>(spike_node, sbA);

    for (int t = 0; t < T_STEPS; ++t) {
        uint32_t* cur = (t & 1) ? sbB : sbA;
        uint32_t* nxt = (t & 1) ? sbA : sbB;
        k_step<<<N_NODES / 4, 128, 0, stream>>>(row_ptr, edata, cur, nxt,
                                                h, v, refc, mn_e, mx_e,
                                                out + NH + (size_t)t * NH,
                                                out, (t == 0) ? 1 : 0,
                                                (t == T_STEPS - 1) ? 1 : 0);
    }
}